// Round 7
// baseline (238.436 us; speedup 1.0000x reference)
//
#include <hip/hip_runtime.h>

// Parametric LIF forward (spike output only).
// x: [B=64, T=64, N=8192] fp32.  out: same shape, values in {0,1}.
// Recurrence per (b,n):  u = last*sig + x[t];  s = (u >= th);
//                        last = (u + lamb*(u-last)) * (1-s)
//
// R4 post-mortem: occupancy 8->32 waves/CU all land ~76-86us (3.4 TB/s) vs
// copy-path 6.3 TB/s. Latency covered 7x over -> not latency. Theory: DRAM
// row locality. 8192 drifting waves x 256B-per-step strided walks fragment
// the address stream -> row-miss-dominated (~50% eff). R5..R7: each wave owns
// a CONTIGUOUS 2 KB chunk per t-step (thread = 2 float4 columns spaced 256
// floats -> 2 back-to-back dwordx4 per step), 256 WGs (all CUs), depth-8
// register pipeline (16 KB in flight per wave).
// R5: __builtin_nontemporal_store rejects HIP float4 -> use ext_vector_type.
// R6: ext_vector elements can't bind to float& -> scalar state array,
//     lif_step by value.
// All FP ops via *_rn intrinsics: forbid FMA contraction, match numpy bitwise
// (output is {0,1}; any spike flip = absmax 1.0).

#define LIF_B 64
#define LIF_T 64
#define LIF_N 8192
#define DPIPE 8           // pipeline depth in t-steps
#define CPT 2             // float4 columns per thread (2 KB per wave-step)

typedef float f4 __attribute__((ext_vector_type(4)));

__global__ __launch_bounds__(256, 4) void lif_fwd_kernel(
    const float* __restrict__ x,
    const float* __restrict__ tau_p,
    const float* __restrict__ lamb_p,
    const float* __restrict__ th_p,
    float* __restrict__ out)
{
    const int tid  = blockIdx.x * blockDim.x + threadIdx.x;
    const int w    = tid >> 6;                 // global wave id, 0..1023
    const int lane = tid & 63;
    const int b    = w >> 4;                   // 16 waves per batch row
    const int n0   = ((w & 15) << 9) + (lane << 2);   // wave chunk*512 + lane*4

    const float sig  = 1.0f / (1.0f + expf(-tau_p[0]));   // 0.5 exact for tau_p=0
    const float lamb = lamb_p[0];
    const float th   = th_p[0];

    // element offset of this thread's first column at t=0; column c adds c*256,
    // time step t adds t*8192.
    const size_t base = (size_t)b * (LIF_T * LIF_N) + n0;

    f4 buf[DPIPE][CPT];
    float st[CPT][4];
#pragma unroll
    for (int c = 0; c < CPT; ++c)
#pragma unroll
        for (int e = 0; e < 4; ++e)
            st[c][e] = 0.0f;

    // Prologue: fill the pipeline.
#pragma unroll
    for (int t = 0; t < DPIPE; ++t)
#pragma unroll
        for (int c = 0; c < CPT; ++c)
            buf[t][c] = *(const f4*)(x + base + (size_t)t * LIF_N + c * 256);

#pragma unroll
    for (int t = 0; t < LIF_T; ++t) {
        // Pull this step's data out of the slot (waits only on loads issued
        // DPIPE steps ago).
        f4 cur[CPT];
#pragma unroll
        for (int c = 0; c < CPT; ++c)
            cur[c] = buf[t & (DPIPE - 1)][c];

        // Refill the slot with step t+DPIPE (issued before this step's stores).
        if (t + DPIPE < LIF_T) {
#pragma unroll
            for (int c = 0; c < CPT; ++c)
                buf[t & (DPIPE - 1)][c] =
                    *(const f4*)(x + base + (size_t)(t + DPIPE) * LIF_N + c * 256);
        }

        // Compute + store (contiguous 2 KB per wave across the 2*CPT dwordx4).
#pragma unroll
        for (int c = 0; c < CPT; ++c) {
            f4 sv;
#pragma unroll
            for (int e = 0; e < 4; ++e) {
                float last = st[c][e];
                float xin  = (e == 0) ? cur[c].x : (e == 1) ? cur[c].y
                           : (e == 2) ? cur[c].z : cur[c].w;
                float u = __fadd_rn(__fmul_rn(last, sig), xin);
                float s = (u >= th) ? 1.0f : 0.0f;
                st[c][e] = __fmul_rn(
                    __fadd_rn(u, __fmul_rn(lamb, __fsub_rn(u, last))),
                    __fsub_rn(1.0f, s));
                if (e == 0) sv.x = s; else if (e == 1) sv.y = s;
                else if (e == 2) sv.z = s; else sv.w = s;
            }
            __builtin_nontemporal_store(sv,
                (f4*)(out + base + (size_t)t * LIF_N + c * 256));
        }
    }
}

extern "C" void kernel_launch(void* const* d_in, const int* in_sizes, int n_in,
                              void* d_out, int out_size, void* d_ws, size_t ws_size,
                              hipStream_t stream) {
    (void)in_sizes; (void)n_in; (void)out_size; (void)d_ws; (void)ws_size;

    const float* x     = (const float*)d_in[0];
    const float* tau_p = (const float*)d_in[1];
    const float* lamb  = (const float*)d_in[2];
    const float* th    = (const float*)d_in[3];
    float*       out   = (float*)d_out;

    const int total_threads = LIF_B * LIF_N / (4 * CPT);   // 65536
    const int block = 256;
    const int grid  = total_threads / block;               // 256

    lif_fwd_kernel<<<grid, block, 0, stream>>>(x, tau_p, lamb, th, out);
}

// Round 8
// 235.612 us; speedup vs baseline: 1.0120x; 1.0120x over previous
//
#include <hip/hip_runtime.h>

// Parametric LIF forward (spike output only).
// x: [B=64, T=64, N=8192] fp32.  out: same shape, values in {0,1}.
// Recurrence per (b,n):  u = last*sig + x[t];  s = (u >= th);
//                        last = (u + lamb*(u-last)) * (1-s)
//
// R1-R7 post-mortem: granule 256B..2KB, occupancy 1..8 waves/SIMD, NT vs
// regular stores, pipe depth 2..16 -> ALL ~75-86us (HBM-side 201 MB at
// ~2.7 TB/s vs fill-kernel 6.7 TB/s). Writes always reach HBM in-kernel
// (R1: WRITE_SIZE=134MB with regular stores). Last live theory: fine-grained
// R/W interleave per channel (bus turnaround + x-region/out-region row
// ping-pong). R8: phase separation — load ALL 64 t-steps into registers
// (64 back-to-back dwordx2, 32 KB same-direction run per wave), then
// compute + 64 back-to-back NT stores.
// All FP ops via *_rn intrinsics: forbid FMA contraction, match numpy bitwise
// (output is {0,1}; any spike flip = absmax 1.0).

#define LIF_B 64
#define LIF_T 64
#define LIF_N 8192
#define NV2 (LIF_N / 2)    // 4096 float2 per row

typedef float f2 __attribute__((ext_vector_type(2)));

__global__ __launch_bounds__(256, 3) void lif_fwd_kernel(
    const f2* __restrict__ x,
    const float* __restrict__ tau_p,
    const float* __restrict__ lamb_p,
    const float* __restrict__ th_p,
    f2* __restrict__ out)
{
    const int tid = blockIdx.x * blockDim.x + threadIdx.x;   // 0 .. B*NV2-1
    const int b   = tid >> 12;                               // tid / 4096
    const int n2  = tid & (NV2 - 1);

    const float sig  = 1.0f / (1.0f + expf(-tau_p[0]));      // 0.5 exact for tau_p=0
    const float lamb = lamb_p[0];
    const float th   = th_p[0];

    const size_t base = (size_t)b * (LIF_T * NV2) + n2;

    // Phase 1: batch-load the ENTIRE time series for this column.
    // 64 independent dwordx2 loads, issued back-to-back (128 VGPRs of dests).
    f2 xv[LIF_T];
#pragma unroll
    for (int t = 0; t < LIF_T; ++t)
        xv[t] = x[base + (size_t)t * NV2];

    // Phase 2: sequential recurrence + dense NT store run.
    // First use waits vmcnt for xv[0] only (in-order retirement), so compute
    // overlaps the load tail; stores form a 64-deep same-direction run.
    float lx = 0.0f, ly = 0.0f;
#pragma unroll
    for (int t = 0; t < LIF_T; ++t) {
        f2 sv;
        {
            float u = __fadd_rn(__fmul_rn(lx, sig), xv[t].x);
            float s = (u >= th) ? 1.0f : 0.0f;
            lx = __fmul_rn(__fadd_rn(u, __fmul_rn(lamb, __fsub_rn(u, lx))),
                           __fsub_rn(1.0f, s));
            sv.x = s;
        }
        {
            float u = __fadd_rn(__fmul_rn(ly, sig), xv[t].y);
            float s = (u >= th) ? 1.0f : 0.0f;
            ly = __fmul_rn(__fadd_rn(u, __fmul_rn(lamb, __fsub_rn(u, ly))),
                           __fsub_rn(1.0f, s));
            sv.y = s;
        }
        __builtin_nontemporal_store(sv, &out[base + (size_t)t * NV2]);
    }
}

extern "C" void kernel_launch(void* const* d_in, const int* in_sizes, int n_in,
                              void* d_out, int out_size, void* d_ws, size_t ws_size,
                              hipStream_t stream) {
    (void)in_sizes; (void)n_in; (void)out_size; (void)d_ws; (void)ws_size;

    const f2*    x     = (const f2*)d_in[0];
    const float* tau_p = (const float*)d_in[1];
    const float* lamb  = (const float*)d_in[2];
    const float* th    = (const float*)d_in[3];
    f2*          out   = (f2*)d_out;

    const int total_threads = LIF_B * NV2;           // 262144
    const int block = 256;
    const int grid  = total_threads / block;         // 1024

    lif_fwd_kernel<<<grid, block, 0, stream>>>(x, tau_p, lamb, th, out);
}